// Round 1
// baseline (195.512 us; speedup 1.0000x reference)
//
#include <hip/hip_runtime.h>
#include <hip/hip_bf16.h>

#define BATCH   32768
#define DIM     2048
#define NHEADS  28
#define NCOLS   280
#define LOSS_SCALE (1.0f / (float)(BATCH * NHEADS))

typedef __attribute__((ext_vector_type(8))) short short8;
typedef __attribute__((ext_vector_type(4))) float f32x4;

__device__ __forceinline__ short f2bf(float f) {
    __hip_bfloat16 h = __float2bfloat16(f);
    union { __hip_bfloat16 h; short s; } u; u.h = h;
    return u.s;
}

// ---------------------------------------------------------------------------
// W pre-swizzle: W [280][2048] f32  ->  Wswz bf16 in MFMA B-fragment order.
// Element index: idx = (((nt*64 + ks)*64 + lane)*8 + j)
//   n = nt*16 + (lane&15)   (column of logits, padded to 288)
//   d = ks*32 + (lane>>4)*8 + j
// One thread produces 8 contiguous bf16 (16B store).
// ---------------------------------------------------------------------------
__global__ void mvh_swz(const float* __restrict__ W, short* __restrict__ Wswz) {
    int t = blockIdx.x * 256 + threadIdx.x;      // 73728 threads
    int lane = t & 63;
    int ks = (t >> 6) & 63;
    int nt = t >> 12;                            // 0..17
    int n = nt * 16 + (lane & 15);
    int d = ks * 32 + (lane >> 4) * 8;
    short8 v;
    #pragma unroll
    for (int j = 0; j < 8; j++) v[j] = 0;
    if (n < NCOLS) {
        const float* src = W + (size_t)n * DIM + d;
        #pragma unroll
        for (int j = 0; j < 8; j++) v[j] = f2bf(src[j]);
    }
    *(short8*)(Wswz + (size_t)t * 8) = v;
}

// ---------------------------------------------------------------------------
// GEMM: logits[b][n] = sum_d hidden[b][d]*W[n][d] + bias[n]
// 256 blocks x 512 threads (8 waves). Wave: nhalf = wave&1 (144-col half),
// wsub = wave>>1 (32-row slice). Per wave: 2 M-subtiles x 9 N-subtiles of
// v_mfma_f32_16x16x32_bf16. A direct from fp32 HBM (cvt in-reg), B direct
// from pre-swizzled bf16 W (L2-resident). 2-deep register double buffer.
// ---------------------------------------------------------------------------
__global__ __launch_bounds__(512, 2)
void mvh_gemm(const float* __restrict__ hidden, const short* __restrict__ Wswz,
              const float* __restrict__ bias, float* __restrict__ logits) {
    const int lane = threadIdx.x & 63;
    const int wave = threadIdx.x >> 6;      // 0..7
    const int nhalf = wave & 1;
    const int wsub = wave >> 1;             // 0..3
    const int l15 = lane & 15;
    const int lhi = lane >> 4;

    const int rowbase = blockIdx.x * 128 + wsub * 32;
    const int colbase = nhalf * 144;

    // A: row = rowbase + m*16 + l15, k = ks*32 + lhi*8 + j
    const float* aptr0 = hidden + (size_t)(rowbase + l15) * DIM + lhi * 8;
    const float* aptr1 = aptr0 + (size_t)16 * DIM;
    // B: Wswz + ((nhalf*9+n)*64 + ks)*512 + lane*8   (short units)
    const short* bptr = Wswz + (size_t)nhalf * 9 * 32768 + (size_t)lane * 8;

    f32x4 acc[2][9];
    #pragma unroll
    for (int m = 0; m < 2; m++)
        #pragma unroll
        for (int n = 0; n < 9; n++)
            acc[m][n] = (f32x4)0.0f;

    f32x4 aA[2][2], aB[2][2];   // [m][lo/hi 4 floats]
    short8 bA[9], bB[9];

#define LOAD_A(dst, ks) do { \
    dst[0][0] = *(const f32x4*)(aptr0 + (ks) * 32); \
    dst[0][1] = *(const f32x4*)(aptr0 + (ks) * 32 + 4); \
    dst[1][0] = *(const f32x4*)(aptr1 + (ks) * 32); \
    dst[1][1] = *(const f32x4*)(aptr1 + (ks) * 32 + 4); \
} while (0)

#define LOAD_B(dst, ks) do { \
    _Pragma("unroll") \
    for (int n = 0; n < 9; n++) \
        dst[n] = *(const short8*)(bptr + (size_t)n * 32768 + (ks) * 512); \
} while (0)

#define COMPUTE(aset, bset) do { \
    short8 ab[2]; \
    _Pragma("unroll") \
    for (int m = 0; m < 2; m++) { \
        _Pragma("unroll") \
        for (int j = 0; j < 4; j++) { \
            ab[m][j]     = f2bf(aset[m][0][j]); \
            ab[m][j + 4] = f2bf(aset[m][1][j]); \
        } \
    } \
    _Pragma("unroll") \
    for (int n = 0; n < 9; n++) \
        _Pragma("unroll") \
        for (int m = 0; m < 2; m++) \
            acc[m][n] = __builtin_amdgcn_mfma_f32_16x16x32_bf16(ab[m], bset[n], acc[m][n], 0, 0, 0); \
} while (0)

    LOAD_A(aA, 0);
    LOAD_B(bA, 0);
    #pragma unroll 1
    for (int ks = 0; ks < 62; ks += 2) {
        LOAD_A(aB, ks + 1);
        LOAD_B(bB, ks + 1);
        COMPUTE(aA, bA);
        LOAD_A(aA, ks + 2);
        LOAD_B(bA, ks + 2);
        COMPUTE(aB, bB);
    }
    LOAD_A(aB, 63);
    LOAD_B(bB, 63);
    COMPUTE(aA, bA);
    COMPUTE(aB, bB);

#undef LOAD_A
#undef LOAD_B
#undef COMPUTE

    // epilogue: bias + store. D layout: row = (lane>>4)*4 + r, col = lane&15.
    float bv[9];
    #pragma unroll
    for (int n = 0; n < 9; n++) {
        int c = colbase + n * 16 + l15;
        bv[n] = (c < NCOLS) ? bias[c] : 0.0f;
    }
    #pragma unroll
    for (int m = 0; m < 2; m++) {
        #pragma unroll
        for (int n = 0; n < 9; n++) {
            int c = colbase + n * 16 + l15;
            if (c < NCOLS) {
                #pragma unroll
                for (int r = 0; r < 4; r++) {
                    int row = rowbase + m * 16 + lhi * 4 + r;
                    logits[(size_t)row * NCOLS + c] = acc[m][n][r] + bv[n];
                }
            }
        }
    }
}

// ---------------------------------------------------------------------------
// Loss: one thread per (row, head). nll = logsumexp(10) - x[label].
// Block-reduce, one float atomicAdd per block into d_out[0].
// ---------------------------------------------------------------------------
__global__ __launch_bounds__(256)
void mvh_loss(const float* __restrict__ logits, const int* __restrict__ labels,
              float* __restrict__ loss_out) {
    int gid = blockIdx.x * 256 + threadIdx.x;    // 917504 = 3584*256 exactly
    const float* p = logits + (size_t)gid * 10;
    float x[10];
    #pragma unroll
    for (int j = 0; j < 10; j++) x[j] = p[j];
    float m = x[0];
    #pragma unroll
    for (int j = 1; j < 10; j++) m = fmaxf(m, x[j]);
    float s = 0.0f;
    #pragma unroll
    for (int j = 0; j < 10; j++) s += __expf(x[j] - m);
    int lab = labels[gid];
    float xl = x[0];
    #pragma unroll
    for (int j = 1; j < 10; j++) xl = (lab == j) ? x[j] : xl;
    float nll = m + __logf(s) - xl;

    #pragma unroll
    for (int off = 32; off > 0; off >>= 1)
        nll += __shfl_down(nll, off, 64);

    __shared__ float part[4];
    int lane = threadIdx.x & 63, wv = threadIdx.x >> 6;
    if (lane == 0) part[wv] = nll;
    __syncthreads();
    if (threadIdx.x == 0)
        atomicAdd(loss_out, (part[0] + part[1] + part[2] + part[3]) * LOSS_SCALE);
}

extern "C" void kernel_launch(void* const* d_in, const int* in_sizes, int n_in,
                              void* d_out, int out_size, void* d_ws, size_t ws_size,
                              hipStream_t stream) {
    const float* hidden = (const float*)d_in[0];
    const int* labels   = (const int*)d_in[1];
    const float* W      = (const float*)d_in[2];
    const float* bias   = (const float*)d_in[3];
    float* out = (float*)d_out;
    short* Wswz = (short*)d_ws;   // 589824 bf16 = 2.25 MB

    hipMemsetAsync(d_out, 0, sizeof(float), stream);           // zero loss accumulator
    mvh_swz<<<288, 256, 0, stream>>>(W, Wswz);
    mvh_gemm<<<256, 512, 0, stream>>>(hidden, Wswz, bias, out + 1);
    mvh_loss<<<3584, 256, 0, stream>>>(out + 1, labels, out);
}

// Round 2
// 146.503 us; speedup vs baseline: 1.3345x; 1.3345x over previous
//
#include <hip/hip_runtime.h>
#include <hip/hip_bf16.h>

#define BATCH   32768
#define DIM     2048
#define NHEADS  28
#define NCOLS   280
#define LOSS_SCALE (1.0f / (float)(BATCH * NHEADS))

typedef __attribute__((ext_vector_type(8))) short short8;
typedef __attribute__((ext_vector_type(4))) float f32x4;

__device__ __forceinline__ short f2bf(float f) {
    __hip_bfloat16 h = __float2bfloat16(f);
    union { __hip_bfloat16 h; short s; } u; u.h = h;
    return u.s;
}

// ---------------------------------------------------------------------------
// W pre-swizzle: W [280][2048] f32 -> Wswz bf16 in MFMA B-fragment order.
//   idx = (((nt*64 + ks)*64 + lane)*8 + j)
//   n = nt*16 + (lane&15), d = ks*32 + (lane>>4)*8 + j
// ---------------------------------------------------------------------------
__global__ void mvh_swz(const float* __restrict__ W, short* __restrict__ Wswz) {
    int t = blockIdx.x * 256 + threadIdx.x;      // 73728 threads
    int lane = t & 63;
    int ks = (t >> 6) & 63;
    int nt = t >> 12;                            // 0..17
    int n = nt * 16 + (lane & 15);
    int d = ks * 32 + (lane >> 4) * 8;
    short8 v;
    #pragma unroll
    for (int j = 0; j < 8; j++) v[j] = 0;
    if (n < NCOLS) {
        const float* src = W + (size_t)n * DIM + d;
        #pragma unroll
        for (int j = 0; j < 8; j++) v[j] = f2bf(src[j]);
    }
    *(short8*)(Wswz + (size_t)t * 8) = v;
}

// ---------------------------------------------------------------------------
// GEMM: logits[b][n] = sum_d hidden[b][d]*W[n][d] + bias[n]
// 512 blocks x 256 threads (4 waves). BM=64, BK=64, 32 K-tiles.
// A: fp32 staged to LDS via global_load_lds (16B), double-buffered,
//    XOR-32B swizzle (source-side pre-swizzle + swizzled ds_read).
// B: registers direct from L2-resident pre-swizzled Wswz.
// Wave (w=0..3): wsub = w>>1 (32-row slice), nhalf = w&1 (144-col half).
// Per wave: 2 M x 9 N subtiles of v_mfma_f32_16x16x32_bf16.
// ---------------------------------------------------------------------------
__global__ __launch_bounds__(256, 2)
void mvh_gemm(const float* __restrict__ hidden, const short* __restrict__ Wswz,
              const float* __restrict__ bias, float* __restrict__ logits) {
    __shared__ float Abuf[2][4096];   // [buf][64 rows * 64 cols] fp32, 32 KB

    const int lane = threadIdx.x & 63;
    const int wave = threadIdx.x >> 6;      // 0..3
    const int nhalf = wave & 1;
    const int wsub = wave >> 1;             // 0..1
    const int l15 = lane & 15;
    const int lhi = lane >> 4;

    const int rowbase = blockIdx.x * 64;
    const int colbase = nhalf * 144;

    const short* bptr = Wswz + (size_t)nhalf * 9 * 32768 + (size_t)lane * 8;

    f32x4 acc[2][9];
    #pragma unroll
    for (int m = 0; m < 2; m++)
        #pragma unroll
        for (int n = 0; n < 9; n++)
            acc[m][n] = (f32x4)0.0f;

    // --- staging: thread t, issue i covers LDS bytes i*4096 + t*16 ---
    // LDS (row_l, bc) holds global float col (bc ^ ((row_l&7)<<5))/4
#define STAGE(bufsel, kt) do { \
    const float* gbase_ = hidden + (size_t)rowbase * DIM + (kt) * 64; \
    _Pragma("unroll") \
    for (int i = 0; i < 4; i++) { \
        int row_l = i * 16 + ((int)threadIdx.x >> 4); \
        int gbyte = (((int)threadIdx.x & 15) * 16) ^ ((row_l & 7) << 5); \
        const float* gp = gbase_ + (size_t)row_l * DIM + (gbyte >> 2); \
        char* lp = (char*)(&Abuf[bufsel][0]) + i * 4096 + (int)threadIdx.x * 16; \
        __builtin_amdgcn_global_load_lds( \
            (const __attribute__((address_space(1))) void*)gp, \
            (__attribute__((address_space(3))) void*)lp, 16, 0, 0); \
    } \
} while (0)

#define LOADB(Bfr, kt) do { \
    _Pragma("unroll") \
    for (int n = 0; n < 9; n++) \
        _Pragma("unroll") \
        for (int ks = 0; ks < 2; ks++) \
            Bfr[n * 2 + ks] = *(const short8*)(bptr + (size_t)n * 32768 + ((kt) * 2 + ks) * 512); \
} while (0)

    // A-frag: row = wsub*32 + m*16 + l15, k-bytes (ks*128 + lhi*32) ^ swz(row)
#define COMPUTE(bufsel, Bfr) do { \
    _Pragma("unroll") \
    for (int ks = 0; ks < 2; ks++) { \
        short8 af[2]; \
        _Pragma("unroll") \
        for (int m = 0; m < 2; m++) { \
            int row_ = wsub * 32 + m * 16 + l15; \
            int kb_ = (ks * 128 + lhi * 32) ^ ((row_ & 7) << 5); \
            const char* base_ = (const char*)(&Abuf[bufsel][0]) + row_ * 256 + kb_; \
            f32x4 lo = *(const f32x4*)base_; \
            f32x4 hi = *(const f32x4*)(base_ + 16); \
            _Pragma("unroll") \
            for (int j = 0; j < 4; j++) { af[m][j] = f2bf(lo[j]); af[m][j + 4] = f2bf(hi[j]); } \
        } \
        _Pragma("unroll") \
        for (int n = 0; n < 9; n++) \
            _Pragma("unroll") \
            for (int m = 0; m < 2; m++) \
                acc[m][n] = __builtin_amdgcn_mfma_f32_16x16x32_bf16(af[m], Bfr[n * 2 + ks], acc[m][n], 0, 0, 0); \
    } \
} while (0)

    short8 B[18];

    STAGE(0, 0);
    #pragma unroll 1
    for (int t = 0; t < 32; t += 2) {
        __syncthreads();                        // Abuf[0] (tile t) staged
        LOADB(B, t);                            // B first: L2, retires before HBM staging
        __builtin_amdgcn_sched_barrier(0);
        STAGE(1, t + 1);
        __builtin_amdgcn_sched_barrier(0);
        COMPUTE(0, B);
        __syncthreads();                        // Abuf[1] (tile t+1) staged
        LOADB(B, t + 1);
        __builtin_amdgcn_sched_barrier(0);
        if (t + 2 < 32) STAGE(0, t + 2);
        __builtin_amdgcn_sched_barrier(0);
        COMPUTE(1, B);
    }

#undef STAGE
#undef LOADB
#undef COMPUTE

    // epilogue: bias + store. D layout: row = (lane>>4)*4 + r, col = lane&15.
    #pragma unroll
    for (int n = 0; n < 9; n++) {
        int c = colbase + n * 16 + l15;
        if (c < NCOLS) {
            float bv = bias[c];
            #pragma unroll
            for (int m = 0; m < 2; m++) {
                #pragma unroll
                for (int r = 0; r < 4; r++) {
                    int row = rowbase + wsub * 32 + m * 16 + lhi * 4 + r;
                    logits[(size_t)row * NCOLS + c] = acc[m][n][r] + bv;
                }
            }
        }
    }
}

// ---------------------------------------------------------------------------
// Loss: one thread per (row, head). nll = logsumexp(10) - x[label].
// ---------------------------------------------------------------------------
__global__ __launch_bounds__(256)
void mvh_loss(const float* __restrict__ logits, const int* __restrict__ labels,
              float* __restrict__ loss_out) {
    int gid = blockIdx.x * 256 + threadIdx.x;    // 917504 = 3584*256 exactly
    const float* p = logits + (size_t)gid * 10;
    float x[10];
    #pragma unroll
    for (int j = 0; j < 10; j++) x[j] = p[j];
    float m = x[0];
    #pragma unroll
    for (int j = 1; j < 10; j++) m = fmaxf(m, x[j]);
    float s = 0.0f;
    #pragma unroll
    for (int j = 0; j < 10; j++) s += __expf(x[j] - m);
    int lab = labels[gid];
    float xl = x[0];
    #pragma unroll
    for (int j = 1; j < 10; j++) xl = (lab == j) ? x[j] : xl;
    float nll = m + __logf(s) - xl;

    #pragma unroll
    for (int off = 32; off > 0; off >>= 1)
        nll += __shfl_down(nll, off, 64);

    __shared__ float part[4];
    int lane = threadIdx.x & 63, wv = threadIdx.x >> 6;
    if (lane == 0) part[wv] = nll;
    __syncthreads();
    if (threadIdx.x == 0)
        atomicAdd(loss_out, (part[0] + part[1] + part[2] + part[3]) * LOSS_SCALE);
}

extern "C" void kernel_launch(void* const* d_in, const int* in_sizes, int n_in,
                              void* d_out, int out_size, void* d_ws, size_t ws_size,
                              hipStream_t stream) {
    const float* hidden = (const float*)d_in[0];
    const int* labels   = (const int*)d_in[1];
    const float* W      = (const float*)d_in[2];
    const float* bias   = (const float*)d_in[3];
    float* out = (float*)d_out;
    short* Wswz = (short*)d_ws;   // 589824 bf16 = 1.18 MB

    hipMemsetAsync(d_out, 0, sizeof(float), stream);           // zero loss accumulator
    mvh_swz<<<288, 256, 0, stream>>>(W, Wswz);
    mvh_gemm<<<512, 256, 0, stream>>>(hidden, Wswz, bias, out + 1);
    mvh_loss<<<3584, 256, 0, stream>>>(out + 1, labels, out);
}